// Round 15
// baseline (59.439 us; speedup 1.0000x reference)
//
#include <hip/hip_runtime.h>
#include <math.h>

#define NB     512
#define NV     6890
#define NF     13776
#define NVHD   20000
#define NPARTS 10
#define NTHREADS 1024
#define NWAVES (NTHREADS/64)
#define CUT    6697                // verts < CUT live in LDS
#define NCHF   ((NF + 63) / 64)    // 216 wave-chunks (faces)
#define NCHH   ((NVHD + 63) / 64)  // 313 wave-chunks (HD)
#define FBLK   ((NF + 255) / 256)  // 54
#define HBLK   ((NVHD + 255) / 256)// 79
// offs: [0..10] face-part starts, [11]=NF, [12]=0, [13]=nCleanH, [14]=NVHD,
//       [15..24] = n_p (per-part HD entry counts, clean+bad)
#define NOFFS  25

// ---- K1: per-wave-chunk key counts (wide, deterministic) ----
__global__ __launch_bounds__(256) void count_kernel(
    const int* __restrict__ faces, const int* __restrict__ part_fid,
    const int* __restrict__ hd_fid,
    int* __restrict__ cntF,   // [11][NCHF]
    int* __restrict__ cntH,   // [2][NCHH]
    int* __restrict__ cntP)   // [10][NCHH]  (HD part histogram)
{
    const int wv = threadIdx.x >> 6, lane = threadIdx.x & 63;
    if (blockIdx.x < FBLK) {
        int c = blockIdx.x * 4 + wv;
        int i = c * 64 + lane;
        int key = -1;
        if (i < NF) {
            int i0 = faces[3*i+0], i1 = faces[3*i+1], i2 = faces[3*i+2];
            bool bad = (i0 >= CUT) || (i1 >= CUT) || (i2 >= CUT);
            key = bad ? 10 : part_fid[i];
        }
        #pragma unroll
        for (int q = 0; q < 11; q++) {
            unsigned long long m = __ballot(key == q);
            if (lane == 0) cntF[q * NCHF + c] = (int)__popcll(m);
        }
    } else {
        int c = (blockIdx.x - FBLK) * 4 + wv;
        if (c < NCHH) {
            int i = c * 64 + lane;
            int key = -1, p = -1;
            if (i < NVHD) {
                int fid = hd_fid[i];
                int i0 = faces[3*fid+0], i1 = faces[3*fid+1], i2 = faces[3*fid+2];
                p = part_fid[fid];
                key = ((i0 >= CUT) || (i1 >= CUT) || (i2 >= CUT)) ? 1 : 0;
            }
            #pragma unroll
            for (int q = 0; q < 2; q++) {
                unsigned long long m = __ballot(key == q);
                if (lane == 0) cntH[q * NCHH + c] = (int)__popcll(m);
            }
            #pragma unroll
            for (int q = 0; q < NPARTS; q++) {
                unsigned long long m = __ballot(p == q);
                if (lane == 0) cntP[q * NCHH + c] = (int)__popcll(m);
            }
        }
    }
}

// ---- K2: tiny scan (1 block): 13 scan rows + 10 histogram totals ----
__global__ __launch_bounds__(1024) void scan_kernel(
    int* __restrict__ cntF, int* __restrict__ cntH, const int* __restrict__ cntP,
    int* __restrict__ offs)
{
    __shared__ int rowtot[13];
    __shared__ int ptot[10];
    const int wv = threadIdx.x >> 6, lane = threadIdx.x & 63;
    if (wv < 11) {
        int* row = cntF + wv * NCHF;
        int carry = 0;
        #pragma unroll
        for (int seg = 0; seg < (NCHF + 63) / 64; seg++) {
            int idx = seg * 64 + lane;
            int v = (idx < NCHF) ? row[idx] : 0;
            int incl = v;
            #pragma unroll
            for (int off = 1; off < 64; off <<= 1) { int n = __shfl_up(incl, off, 64); if (lane >= off) incl += n; }
            if (idx < NCHF) row[idx] = incl - v + carry;
            carry += __shfl(incl, 63, 64);
        }
        if (lane == 0) rowtot[wv] = carry;
    } else if (wv < 13) {
        int r = wv - 11;
        int* row = cntH + r * NCHH;
        int carry = 0;
        #pragma unroll
        for (int seg = 0; seg < (NCHH + 63) / 64; seg++) {
            int idx = seg * 64 + lane;
            int v = (idx < NCHH) ? row[idx] : 0;
            int incl = v;
            #pragma unroll
            for (int off = 1; off < 64; off <<= 1) { int n = __shfl_up(incl, off, 64); if (lane >= off) incl += n; }
            if (idx < NCHH) row[idx] = incl - v + carry;
            carry += __shfl(incl, 63, 64);
        }
        if (lane == 0) rowtot[11 + r] = carry;
    } else if (wv == 13) {
        if (lane < NPARTS) {
            const int* row = cntP + lane * NCHH;
            int s = 0;
            for (int c = 0; c < NCHH; c++) s += row[c];
            ptot[lane] = s;
        }
    }
    __syncthreads();
    if (threadIdx.x == 0) {
        int r = 0;
        #pragma unroll
        for (int q = 0; q < 11; q++) { offs[q] = r; r += rowtot[q]; }
        offs[11] = r;                        // == NF
        offs[12] = 0;
        offs[13] = rowtot[11];               // nCleanH
        offs[14] = rowtot[11] + rowtot[12];  // == NVHD
        #pragma unroll
        for (int q = 0; q < NPARTS; q++) offs[15 + q] = ptot[q];
    }
}

// ---- K3: wide deterministic scatter ----
__global__ __launch_bounds__(256) void scatter_kernel(
    const float* __restrict__ bary, const int* __restrict__ faces,
    const int* __restrict__ hd_fid, const int* __restrict__ part_fid,
    const int* __restrict__ cntF, const int* __restrict__ cntH,
    const int* __restrict__ offs,
    uint2* __restrict__ f_sorted, uint4* __restrict__ hd_sorted)
{
    const int wv = threadIdx.x >> 6, lane = threadIdx.x & 63;
    const unsigned long long low = (1ull << lane) - 1ull;
    if (blockIdx.x < FBLK) {
        int c = blockIdx.x * 4 + wv;
        int i = c * 64 + lane;
        int key = -1; uint2 ft = make_uint2(0u, 0u);
        if (i < NF) {
            int i0 = faces[3*i+0], i1 = faces[3*i+1], i2 = faces[3*i+2];
            int p  = part_fid[i];
            bool bad = (i0 >= CUT) || (i1 >= CUT) || (i2 >= CUT);
            key = bad ? 10 : p;
            ft = make_uint2((unsigned)i0 | ((unsigned)i1 << 16),
                            (unsigned)i2 | ((unsigned)p  << 16));
        }
        #pragma unroll
        for (int q = 0; q < 11; q++) {
            unsigned long long m = __ballot(key == q);
            if (key == q) {
                int rank = (int)__popcll(m & low);
                f_sorted[offs[q] + cntF[q * NCHF + c] + rank] = ft;
            }
        }
    } else {
        int c = (blockIdx.x - FBLK) * 4 + wv;
        if (c < NCHH) {
            int i = c * 64 + lane;
            int key = -1; uint4 hp = make_uint4(0u, 0u, 0u, 0u);
            if (i < NVHD) {
                int fid = hd_fid[i];
                int i0 = faces[3*fid+0], i1 = faces[3*fid+1], i2 = faces[3*fid+2];
                float b0 = bary[3*i+0], b1 = bary[3*i+1], b2 = bary[3*i+2];
                float inv = 1.0f / (b0 + b1 + b2);
                hp = make_uint4((unsigned)i0 | ((unsigned)i1 << 16),
                                (unsigned)i2 | ((unsigned)part_fid[fid] << 16),
                                __float_as_uint(b0*inv), __float_as_uint(b1*inv));
                key = ((i0 >= CUT) || (i1 >= CUT) || (i2 >= CUT)) ? 1 : 0;
            }
            #pragma unroll
            for (int q = 0; q < 2; q++) {
                unsigned long long m = __ballot(key == q);
                if (key == q) {
                    int rank = (int)__popcll(m & low);
                    hd_sorted[offs[12 + q] + cntH[q * NCHH + c] + rank] = hp;
                }
            }
        }
    }
}

__global__ __launch_bounds__(NTHREADS, 8) void stab_kernel(
    const float* __restrict__ vertices,    // [B][V][3] f32
    const uint2* __restrict__ f_sorted,    // [NF] part-sorted, bad suffix
    const uint4* __restrict__ hd_sorted,   // [NVHD] clean prefix, bad suffix
    const int*   __restrict__ offs,
    float*       __restrict__ out)         // [B]
{
    __shared__ float2 sxy[CUT];              // 53576 B
    __shared__ float  szz[CUT];              // 26788 B
    __shared__ float  spart[NPARTS];         // 40 B
    __shared__ float  sredp[NWAVES][NPARTS]; // 640 B
    __shared__ int    soffs[NOFFS];          // 100 B -> ~81150 (2 blocks/CU)

    const int tid  = threadIdx.x;
    const int b    = blockIdx.x;
    const int wave = tid >> 6;
    const int lane = tid & 63;
    const float* __restrict__ vb = vertices + (size_t)b * (NV * 3);

    if (tid < NOFFS) soffs[tid] = offs[tid];

    // ---- Phase A: stage verts [0,CUT) ----
    for (int v = tid; v < CUT; v += NTHREADS) {
        float x = vb[3 * v + 0];
        float y = vb[3 * v + 1];
        float z = vb[3 * v + 2];
        sxy[v] = make_float2(x, y);
        szz[v] = z;
    }
    __syncthreads();

    // ---- Phase B: 10 static per-part sub-loops (1/6 hoisted) ----
    float accp[NPARTS];
    #pragma unroll
    for (int p = 0; p < NPARTS; p++) {
        float va = 0.f;
        #pragma unroll 2
        for (int f = soffs[p] + tid; f < soffs[p + 1]; f += NTHREADS) {
            uint2 ft = f_sorted[f];
            int i0 = ft.x & 0xFFFF, i1 = ft.x >> 16, i2 = ft.y & 0xFFFF;
            float2 t0 = sxy[i0]; float z0 = szz[i0];
            float2 t1 = sxy[i1]; float z1 = szz[i1];
            float2 t2 = sxy[i2]; float z2 = szz[i2];
            float cx = t0.y * z1   - z0   * t1.y;
            float cy = z0   * t1.x - t0.x * z1;
            float cz = t0.x * t1.y - t0.y * t1.x;
            va += cx * t2.x + cy * t2.y + cz * z2;
        }
        accp[p] = va * (1.0f / 6.0f);
    }
    // bad faces (rare): global gathers, runtime binning
    for (int f = soffs[10] + tid; f < NF; f += NTHREADS) {
        uint2 ft = f_sorted[f];
        int i0 = ft.x & 0xFFFF, i1 = ft.x >> 16;
        int i2 = ft.y & 0xFFFF, p  = (int)(ft.y >> 16);
        float x0 = vb[3*i0+0], y0 = vb[3*i0+1], z0 = vb[3*i0+2];
        float x1 = vb[3*i1+0], y1 = vb[3*i1+1], z1 = vb[3*i1+2];
        float x2 = vb[3*i2+0], y2 = vb[3*i2+1], z2 = vb[3*i2+2];
        float cx = y0 * z1 - z0 * y1;
        float cy = z0 * x1 - x0 * z1;
        float cz = x0 * y1 - y0 * x1;
        float vol = (cx * x2 + cy * y2 + cz * z2) * (1.0f / 6.0f);
        #pragma unroll
        for (int q = 0; q < NPARTS; q++) accp[q] += (p == q) ? vol : 0.f;
    }

    // prefetch first Phase-C table entry: its L2 latency hides under the
    // Phase-B reduction (shuffle tree + 2 barriers). hClean ~17K >> 1024.
    const int hClean = soffs[13];
    uint4 hp0 = make_uint4(0u, 0u, 0u, 0u);
    if (tid < hClean) hp0 = hd_sorted[tid];

    #pragma unroll
    for (int q = 0; q < NPARTS; q++) {
        float s = accp[q];
        #pragma unroll
        for (int off = 32; off > 0; off >>= 1) s += __shfl_down(s, off, 64);
        accp[q] = s;
    }
    if (lane == 0) {
        #pragma unroll
        for (int q = 0; q < NPARTS; q++) sredp[wave][q] = accp[q];
    }
    __syncthreads();
    if (tid < NPARTS) {
        float s = 0.f;
        #pragma unroll
        for (int w = 0; w < NWAVES; w++) s += sredp[w][tid];
        spart[tid] = s;
    }
    __syncthreads();

    // ---- Phase C: single clean loop; iteration 0 peeled (prefetched) ----
    float sVx = 0.f, sVz = 0.f;
    float sPx = 0.f, sPz = 0.f, sPw = 0.f;

    if (tid < hClean) {
        uint4 hp = hp0;
        int i0 = hp.x & 0xFFFF, i1 = hp.x >> 16;
        int i2 = hp.y & 0xFFFF, p  = (int)(hp.y >> 16);
        float w0 = __uint_as_float(hp.z);
        float w1 = __uint_as_float(hp.w);
        float w2 = 1.0f - w0 - w1;
        float2 t0 = sxy[i0]; float z0 = szz[i0];
        float2 t1 = sxy[i1]; float z1 = szz[i1];
        float2 t2 = sxy[i2]; float z2 = szz[i2];
        float x = w0 * t0.x + w1 * t1.x + w2 * t2.x;
        float y = w0 * t0.y + w1 * t1.y + w2 * t2.y;
        float z = w0 * z0   + w1 * z1   + w2 * z2;
        float vol = spart[p];
        float pw  = (y < 0.f) ? fmaf(-100.f, y, 1.f) : __expf(-10.f * y);
        sVx += x * vol;  sVz += z * vol;
        sPx += x * pw;   sPz += z * pw;   sPw += pw;
    }

    #pragma unroll 4
    for (int v = tid + NTHREADS; v < hClean; v += NTHREADS) {
        uint4 hp = hd_sorted[v];
        int i0 = hp.x & 0xFFFF, i1 = hp.x >> 16;
        int i2 = hp.y & 0xFFFF, p  = (int)(hp.y >> 16);
        float w0 = __uint_as_float(hp.z);
        float w1 = __uint_as_float(hp.w);
        float w2 = 1.0f - w0 - w1;
        float2 t0 = sxy[i0]; float z0 = szz[i0];
        float2 t1 = sxy[i1]; float z1 = szz[i1];
        float2 t2 = sxy[i2]; float z2 = szz[i2];
        float x = w0 * t0.x + w1 * t1.x + w2 * t2.x;
        float y = w0 * t0.y + w1 * t1.y + w2 * t2.y;
        float z = w0 * z0   + w1 * z1   + w2 * z2;
        float vol = spart[p];
        float pw  = (y < 0.f) ? fmaf(-100.f, y, 1.f) : __expf(-10.f * y);
        sVx += x * vol;  sVz += z * vol;
        sPx += x * pw;   sPz += z * pw;   sPw += pw;
    }
    // bad HD suffix (rare): global gathers
    for (int v = hClean + tid; v < NVHD; v += NTHREADS) {
        uint4 hp = hd_sorted[v];
        int i0 = hp.x & 0xFFFF, i1 = hp.x >> 16;
        int i2 = hp.y & 0xFFFF, p  = (int)(hp.y >> 16);
        float w0 = __uint_as_float(hp.z);
        float w1 = __uint_as_float(hp.w);
        float w2 = 1.0f - w0 - w1;
        float x0 = vb[3*i0+0], y0 = vb[3*i0+1], z0 = vb[3*i0+2];
        float x1 = vb[3*i1+0], y1 = vb[3*i1+1], z1 = vb[3*i1+2];
        float x2 = vb[3*i2+0], y2 = vb[3*i2+1], z2 = vb[3*i2+2];
        float x = w0 * x0 + w1 * x1 + w2 * x2;
        float y = w0 * y0 + w1 * y1 + w2 * y2;
        float z = w0 * z0 + w1 * z1 + w2 * z2;
        float vol = spart[p];
        float pw  = (y < 0.f) ? fmaf(-100.f, y, 1.f) : __expf(-10.f * y);
        sVx += x * vol;  sVz += z * vol;
        sPx += x * pw;   sPz += z * pw;   sPw += pw;
    }

    float vals[5] = {sVx, sVz, sPx, sPz, sPw};
    #pragma unroll
    for (int q = 0; q < 5; q++) {
        float s = vals[q];
        #pragma unroll
        for (int off = 32; off > 0; off >>= 1) s += __shfl_down(s, off, 64);
        vals[q] = s;
    }
    float* sred5 = &sredp[0][0];   // reuse (dead after spart): 320 B
    if (lane == 0) {
        #pragma unroll
        for (int q = 0; q < 5; q++) sred5[wave * 5 + q] = vals[q];
    }
    __syncthreads();
    if (tid == 0) {
        float r[5];
        #pragma unroll
        for (int q = 0; q < 5; q++) {
            float s = 0.f;
            #pragma unroll
            for (int w = 0; w < NWAVES; w++) s += sred5[w * 5 + q];
            r[q] = s;
        }
        float sVol = 0.f;
        #pragma unroll
        for (int p = 0; p < NPARTS; p++) sVol += spart[p] * (float)soffs[15 + p];
        float invVol = 1.0f / sVol;
        float invPw  = 1.0f / (r[4] + 1e-6f);
        float comx = r[0] * invVol, comz = r[1] * invVol;
        float copx = r[2] * invPw,  copz = r[3] * invPw;
        float d0 = comx - copx, d2 = comz - copz;
        out[b] = sqrtf(d0 * d0 + d2 * d2);
    }
}

extern "C" void kernel_launch(void* const* d_in, const int* in_sizes, int n_in,
                              void* d_out, int out_size, void* d_ws, size_t ws_size,
                              hipStream_t stream) {
    const float* vertices = (const float*)d_in[0];
    const float* bary     = (const float*)d_in[1];
    const int*   faces    = (const int*)d_in[2];
    const int*   hd_fid   = (const int*)d_in[3];
    const int*   part_fid = (const int*)d_in[4];
    float* out = (float*)d_out;

    // ws layout: hd_sorted(16B) | f_sorted | cntF | cntH | cntP | offs
    char* ws = (char*)d_ws;
    uint4* hd_sorted = (uint4*)ws;                                   // 320000
    uint2* f_sorted  = (uint2*)(ws + 320000);                        // 110208
    int*   cntF      = (int*)(ws + 320000 + 110208);                 // 9504
    int*   cntH      = (int*)(ws + 320000 + 110208 + 9504);          // 2504
    int*   cntP      = (int*)(ws + 320000 + 110208 + 9504 + 2504);   // 12520
    int*   offs      = (int*)(ws + 320000 + 110208 + 9504 + 2504 + 12520); // 25*4

    count_kernel<<<FBLK + HBLK, 256, 0, stream>>>(faces, part_fid, hd_fid, cntF, cntH, cntP);
    scan_kernel<<<1, 1024, 0, stream>>>(cntF, cntH, cntP, offs);
    scatter_kernel<<<FBLK + HBLK, 256, 0, stream>>>(bary, faces, hd_fid, part_fid,
                                                    cntF, cntH, offs, f_sorted, hd_sorted);
    stab_kernel<<<NB, NTHREADS, 0, stream>>>(vertices, f_sorted, hd_sorted, offs, out);
}

// Round 16
// 57.102 us; speedup vs baseline: 1.0409x; 1.0409x over previous
//
#include <hip/hip_runtime.h>
#include <math.h>

#define NB     512
#define NV     6890
#define NF     13776
#define NVHD   20000
#define NPARTS 10
#define NTHREADS 1024
#define NWAVES (NTHREADS/64)
#define CUT    6697                // verts < CUT live in LDS
#define NCHF   ((NF + 63) / 64)    // 216 wave-chunks (faces)
#define NCHH   ((NVHD + 63) / 64)  // 313 wave-chunks (HD)
#define FBLK   ((NF + 255) / 256)  // 54
#define HBLK   ((NVHD + 255) / 256)// 79
// offs: [0..10] face-part starts, [11]=NF, [12]=0, [13]=nCleanH, [14]=NVHD,
//       [15..24] = n_p (per-part HD entry counts, clean+bad)
#define NOFFS  25

// ---- K1: per-wave-chunk key counts (wide, deterministic) ----
__global__ __launch_bounds__(256) void count_kernel(
    const int* __restrict__ faces, const int* __restrict__ part_fid,
    const int* __restrict__ hd_fid,
    int* __restrict__ cntF,   // [11][NCHF]
    int* __restrict__ cntH,   // [2][NCHH]
    int* __restrict__ cntP)   // [10][NCHH]  (HD part histogram)
{
    const int wv = threadIdx.x >> 6, lane = threadIdx.x & 63;
    if (blockIdx.x < FBLK) {
        int c = blockIdx.x * 4 + wv;
        int i = c * 64 + lane;
        int key = -1;
        if (i < NF) {
            int i0 = faces[3*i+0], i1 = faces[3*i+1], i2 = faces[3*i+2];
            bool bad = (i0 >= CUT) || (i1 >= CUT) || (i2 >= CUT);
            key = bad ? 10 : part_fid[i];
        }
        #pragma unroll
        for (int q = 0; q < 11; q++) {
            unsigned long long m = __ballot(key == q);
            if (lane == 0) cntF[q * NCHF + c] = (int)__popcll(m);
        }
    } else {
        int c = (blockIdx.x - FBLK) * 4 + wv;
        if (c < NCHH) {
            int i = c * 64 + lane;
            int key = -1, p = -1;
            if (i < NVHD) {
                int fid = hd_fid[i];
                int i0 = faces[3*fid+0], i1 = faces[3*fid+1], i2 = faces[3*fid+2];
                p = part_fid[fid];
                key = ((i0 >= CUT) || (i1 >= CUT) || (i2 >= CUT)) ? 1 : 0;
            }
            #pragma unroll
            for (int q = 0; q < 2; q++) {
                unsigned long long m = __ballot(key == q);
                if (lane == 0) cntH[q * NCHH + c] = (int)__popcll(m);
            }
            #pragma unroll
            for (int q = 0; q < NPARTS; q++) {
                unsigned long long m = __ballot(p == q);
                if (lane == 0) cntP[q * NCHH + c] = (int)__popcll(m);
            }
        }
    }
}

// ---- K2: tiny scan (1 block): 13 scan rows + 10 histogram totals ----
__global__ __launch_bounds__(1024) void scan_kernel(
    int* __restrict__ cntF, int* __restrict__ cntH, const int* __restrict__ cntP,
    int* __restrict__ offs)
{
    __shared__ int rowtot[13];
    __shared__ int ptot[10];
    const int wv = threadIdx.x >> 6, lane = threadIdx.x & 63;
    if (wv < 11) {
        int* row = cntF + wv * NCHF;
        int carry = 0;
        #pragma unroll
        for (int seg = 0; seg < (NCHF + 63) / 64; seg++) {
            int idx = seg * 64 + lane;
            int v = (idx < NCHF) ? row[idx] : 0;
            int incl = v;
            #pragma unroll
            for (int off = 1; off < 64; off <<= 1) { int n = __shfl_up(incl, off, 64); if (lane >= off) incl += n; }
            if (idx < NCHF) row[idx] = incl - v + carry;
            carry += __shfl(incl, 63, 64);
        }
        if (lane == 0) rowtot[wv] = carry;
    } else if (wv < 13) {
        int r = wv - 11;
        int* row = cntH + r * NCHH;
        int carry = 0;
        #pragma unroll
        for (int seg = 0; seg < (NCHH + 63) / 64; seg++) {
            int idx = seg * 64 + lane;
            int v = (idx < NCHH) ? row[idx] : 0;
            int incl = v;
            #pragma unroll
            for (int off = 1; off < 64; off <<= 1) { int n = __shfl_up(incl, off, 64); if (lane >= off) incl += n; }
            if (idx < NCHH) row[idx] = incl - v + carry;
            carry += __shfl(incl, 63, 64);
        }
        if (lane == 0) rowtot[11 + r] = carry;
    } else if (wv == 13) {
        if (lane < NPARTS) {
            const int* row = cntP + lane * NCHH;
            int s = 0;
            for (int c = 0; c < NCHH; c++) s += row[c];
            ptot[lane] = s;
        }
    }
    __syncthreads();
    if (threadIdx.x == 0) {
        int r = 0;
        #pragma unroll
        for (int q = 0; q < 11; q++) { offs[q] = r; r += rowtot[q]; }
        offs[11] = r;                        // == NF
        offs[12] = 0;
        offs[13] = rowtot[11];               // nCleanH
        offs[14] = rowtot[11] + rowtot[12];  // == NVHD
        #pragma unroll
        for (int q = 0; q < NPARTS; q++) offs[15 + q] = ptot[q];
    }
}

// ---- K3: wide deterministic scatter ----
__global__ __launch_bounds__(256) void scatter_kernel(
    const float* __restrict__ bary, const int* __restrict__ faces,
    const int* __restrict__ hd_fid, const int* __restrict__ part_fid,
    const int* __restrict__ cntF, const int* __restrict__ cntH,
    const int* __restrict__ offs,
    uint2* __restrict__ f_sorted, uint4* __restrict__ hd_sorted)
{
    const int wv = threadIdx.x >> 6, lane = threadIdx.x & 63;
    const unsigned long long low = (1ull << lane) - 1ull;
    if (blockIdx.x < FBLK) {
        int c = blockIdx.x * 4 + wv;
        int i = c * 64 + lane;
        int key = -1; uint2 ft = make_uint2(0u, 0u);
        if (i < NF) {
            int i0 = faces[3*i+0], i1 = faces[3*i+1], i2 = faces[3*i+2];
            int p  = part_fid[i];
            bool bad = (i0 >= CUT) || (i1 >= CUT) || (i2 >= CUT);
            key = bad ? 10 : p;
            ft = make_uint2((unsigned)i0 | ((unsigned)i1 << 16),
                            (unsigned)i2 | ((unsigned)p  << 16));
        }
        #pragma unroll
        for (int q = 0; q < 11; q++) {
            unsigned long long m = __ballot(key == q);
            if (key == q) {
                int rank = (int)__popcll(m & low);
                f_sorted[offs[q] + cntF[q * NCHF + c] + rank] = ft;
            }
        }
    } else {
        int c = (blockIdx.x - FBLK) * 4 + wv;
        if (c < NCHH) {
            int i = c * 64 + lane;
            int key = -1; uint4 hp = make_uint4(0u, 0u, 0u, 0u);
            if (i < NVHD) {
                int fid = hd_fid[i];
                int i0 = faces[3*fid+0], i1 = faces[3*fid+1], i2 = faces[3*fid+2];
                float b0 = bary[3*i+0], b1 = bary[3*i+1], b2 = bary[3*i+2];
                float inv = 1.0f / (b0 + b1 + b2);
                hp = make_uint4((unsigned)i0 | ((unsigned)i1 << 16),
                                (unsigned)i2 | ((unsigned)part_fid[fid] << 16),
                                __float_as_uint(b0*inv), __float_as_uint(b1*inv));
                key = ((i0 >= CUT) || (i1 >= CUT) || (i2 >= CUT)) ? 1 : 0;
            }
            #pragma unroll
            for (int q = 0; q < 2; q++) {
                unsigned long long m = __ballot(key == q);
                if (key == q) {
                    int rank = (int)__popcll(m & low);
                    hd_sorted[offs[12 + q] + cntH[q * NCHH + c] + rank] = hp;
                }
            }
        }
    }
}

__global__ __launch_bounds__(NTHREADS, 8) void stab_kernel(
    const float* __restrict__ vertices,    // [B][V][3] f32
    const uint2* __restrict__ f_sorted,    // [NF] part-sorted, bad suffix
    const uint4* __restrict__ hd_sorted,   // [NVHD] clean prefix, bad suffix
    const int*   __restrict__ offs,
    float*       __restrict__ out)         // [B]
{
    __shared__ float2 sxy[CUT];              // 53576 B
    __shared__ float  szz[CUT];              // 26788 B
    __shared__ float  spart[NPARTS];         // 40 B
    __shared__ float  sredp[NWAVES][NPARTS]; // 640 B
    __shared__ int    soffs[NOFFS];          // 100 B -> ~81150 (2 blocks/CU)

    const int tid  = threadIdx.x;
    const int b    = blockIdx.x;
    const int wave = tid >> 6;
    const int lane = tid & 63;
    const float* __restrict__ vb = vertices + (size_t)b * (NV * 3);

    if (tid < NOFFS) soffs[tid] = offs[tid];

    // ---- Phase A: stage verts [0,CUT) ----
    for (int v = tid; v < CUT; v += NTHREADS) {
        float x = vb[3 * v + 0];
        float y = vb[3 * v + 1];
        float z = vb[3 * v + 2];
        sxy[v] = make_float2(x, y);
        szz[v] = z;
    }
    __syncthreads();

    // ---- Phase B: 10 static per-part sub-loops (1/6 hoisted) ----
    float accp[NPARTS];
    #pragma unroll
    for (int p = 0; p < NPARTS; p++) {
        float va = 0.f;
        for (int f = soffs[p] + tid; f < soffs[p + 1]; f += NTHREADS) {
            uint2 ft = f_sorted[f];
            int i0 = ft.x & 0xFFFF, i1 = ft.x >> 16, i2 = ft.y & 0xFFFF;
            float2 t0 = sxy[i0]; float z0 = szz[i0];
            float2 t1 = sxy[i1]; float z1 = szz[i1];
            float2 t2 = sxy[i2]; float z2 = szz[i2];
            float cx = t0.y * z1   - z0   * t1.y;
            float cy = z0   * t1.x - t0.x * z1;
            float cz = t0.x * t1.y - t0.y * t1.x;
            va += cx * t2.x + cy * t2.y + cz * z2;
        }
        accp[p] = va * (1.0f / 6.0f);
    }
    // bad faces (rare): global gathers, runtime binning
    for (int f = soffs[10] + tid; f < NF; f += NTHREADS) {
        uint2 ft = f_sorted[f];
        int i0 = ft.x & 0xFFFF, i1 = ft.x >> 16;
        int i2 = ft.y & 0xFFFF, p  = (int)(ft.y >> 16);
        float x0 = vb[3*i0+0], y0 = vb[3*i0+1], z0 = vb[3*i0+2];
        float x1 = vb[3*i1+0], y1 = vb[3*i1+1], z1 = vb[3*i1+2];
        float x2 = vb[3*i2+0], y2 = vb[3*i2+1], z2 = vb[3*i2+2];
        float cx = y0 * z1 - z0 * y1;
        float cy = z0 * x1 - x0 * z1;
        float cz = x0 * y1 - y0 * x1;
        float vol = (cx * x2 + cy * y2 + cz * z2) * (1.0f / 6.0f);
        #pragma unroll
        for (int q = 0; q < NPARTS; q++) accp[q] += (p == q) ? vol : 0.f;
    }

    #pragma unroll
    for (int q = 0; q < NPARTS; q++) {
        float s = accp[q];
        #pragma unroll
        for (int off = 32; off > 0; off >>= 1) s += __shfl_down(s, off, 64);
        accp[q] = s;
    }
    if (lane == 0) {
        #pragma unroll
        for (int q = 0; q < NPARTS; q++) sredp[wave][q] = accp[q];
    }
    __syncthreads();
    if (tid < NPARTS) {
        float s = 0.f;
        #pragma unroll
        for (int w = 0; w < NWAVES; w++) s += sredp[w][tid];
        spart[tid] = s;
    }
    __syncthreads();

    // ---- Phase C: single clean loop, sVol via n_p ----
    float sVx = 0.f, sVz = 0.f;
    float sPx = 0.f, sPz = 0.f, sPw = 0.f;
    const int hClean = soffs[13];

    #pragma unroll 2
    for (int v = tid; v < hClean; v += NTHREADS) {
        uint4 hp = hd_sorted[v];
        int i0 = hp.x & 0xFFFF, i1 = hp.x >> 16;
        int i2 = hp.y & 0xFFFF, p  = (int)(hp.y >> 16);
        float w0 = __uint_as_float(hp.z);
        float w1 = __uint_as_float(hp.w);
        float w2 = 1.0f - w0 - w1;
        float2 t0 = sxy[i0]; float z0 = szz[i0];
        float2 t1 = sxy[i1]; float z1 = szz[i1];
        float2 t2 = sxy[i2]; float z2 = szz[i2];
        float x = w0 * t0.x + w1 * t1.x + w2 * t2.x;
        float y = w0 * t0.y + w1 * t1.y + w2 * t2.y;
        float z = w0 * z0   + w1 * z1   + w2 * z2;
        float vol = spart[p];
        float pw  = (y < 0.f) ? fmaf(-100.f, y, 1.f) : __expf(-10.f * y);
        sVx += x * vol;  sVz += z * vol;
        sPx += x * pw;   sPz += z * pw;   sPw += pw;
    }
    // bad HD suffix (rare): global gathers
    for (int v = hClean + tid; v < NVHD; v += NTHREADS) {
        uint4 hp = hd_sorted[v];
        int i0 = hp.x & 0xFFFF, i1 = hp.x >> 16;
        int i2 = hp.y & 0xFFFF, p  = (int)(hp.y >> 16);
        float w0 = __uint_as_float(hp.z);
        float w1 = __uint_as_float(hp.w);
        float w2 = 1.0f - w0 - w1;
        float x0 = vb[3*i0+0], y0 = vb[3*i0+1], z0 = vb[3*i0+2];
        float x1 = vb[3*i1+0], y1 = vb[3*i1+1], z1 = vb[3*i1+2];
        float x2 = vb[3*i2+0], y2 = vb[3*i2+1], z2 = vb[3*i2+2];
        float x = w0 * x0 + w1 * x1 + w2 * x2;
        float y = w0 * y0 + w1 * y1 + w2 * y2;
        float z = w0 * z0 + w1 * z1 + w2 * z2;
        float vol = spart[p];
        float pw  = (y < 0.f) ? fmaf(-100.f, y, 1.f) : __expf(-10.f * y);
        sVx += x * vol;  sVz += z * vol;
        sPx += x * pw;   sPz += z * pw;   sPw += pw;
    }

    float vals[5] = {sVx, sVz, sPx, sPz, sPw};
    #pragma unroll
    for (int q = 0; q < 5; q++) {
        float s = vals[q];
        #pragma unroll
        for (int off = 32; off > 0; off >>= 1) s += __shfl_down(s, off, 64);
        vals[q] = s;
    }
    float* sred5 = &sredp[0][0];   // reuse (dead after spart): 320 B
    if (lane == 0) {
        #pragma unroll
        for (int q = 0; q < 5; q++) sred5[wave * 5 + q] = vals[q];
    }
    __syncthreads();
    if (tid == 0) {
        float r[5];
        #pragma unroll
        for (int q = 0; q < 5; q++) {
            float s = 0.f;
            #pragma unroll
            for (int w = 0; w < NWAVES; w++) s += sred5[w * 5 + q];
            r[q] = s;
        }
        float sVol = 0.f;
        #pragma unroll
        for (int p = 0; p < NPARTS; p++) sVol += spart[p] * (float)soffs[15 + p];
        float invVol = 1.0f / sVol;
        float invPw  = 1.0f / (r[4] + 1e-6f);
        float comx = r[0] * invVol, comz = r[1] * invVol;
        float copx = r[2] * invPw,  copz = r[3] * invPw;
        float d0 = comx - copx, d2 = comz - copz;
        out[b] = sqrtf(d0 * d0 + d2 * d2);
    }
}

extern "C" void kernel_launch(void* const* d_in, const int* in_sizes, int n_in,
                              void* d_out, int out_size, void* d_ws, size_t ws_size,
                              hipStream_t stream) {
    const float* vertices = (const float*)d_in[0];
    const float* bary     = (const float*)d_in[1];
    const int*   faces    = (const int*)d_in[2];
    const int*   hd_fid   = (const int*)d_in[3];
    const int*   part_fid = (const int*)d_in[4];
    float* out = (float*)d_out;

    // ws layout: hd_sorted(16B) | f_sorted | cntF | cntH | cntP | offs
    char* ws = (char*)d_ws;
    uint4* hd_sorted = (uint4*)ws;                                   // 320000
    uint2* f_sorted  = (uint2*)(ws + 320000);                        // 110208
    int*   cntF      = (int*)(ws + 320000 + 110208);                 // 9504
    int*   cntH      = (int*)(ws + 320000 + 110208 + 9504);          // 2504
    int*   cntP      = (int*)(ws + 320000 + 110208 + 9504 + 2504);   // 12520
    int*   offs      = (int*)(ws + 320000 + 110208 + 9504 + 2504 + 12520); // 25*4

    count_kernel<<<FBLK + HBLK, 256, 0, stream>>>(faces, part_fid, hd_fid, cntF, cntH, cntP);
    scan_kernel<<<1, 1024, 0, stream>>>(cntF, cntH, cntP, offs);
    scatter_kernel<<<FBLK + HBLK, 256, 0, stream>>>(bary, faces, hd_fid, part_fid,
                                                    cntF, cntH, offs, f_sorted, hd_sorted);
    stab_kernel<<<NB, NTHREADS, 0, stream>>>(vertices, f_sorted, hd_sorted, offs, out);
}